// Round 1
// baseline (16454.745 us; speedup 1.0000x reference)
//
#include <hip/hip_runtime.h>
#include <math.h>
#include <float.h>

// DecoderModel: 1024-step pointer-network decode.
// Persistent cooperative-style kernel, 128 blocks x 256 threads, one
// hand-rolled grid barrier per step. Weights are partitioned so each XCD's
// blocks touch only ~3MB -> L2-resident. All cross-block mutable state goes
// through AGENT-scope atomics (L1/L2 bypass) so weight lines stay cached.

#define SEQ   1024
#define FEAT  256
#define HID   1024
#define ONUM  1024
#define NB    128
#define TPB   256

#define AGENT __HIP_MEMORY_SCOPE_AGENT

struct Ws {
  float h[2][HID];        // double-buffered hidden state
  float part_sum[NB];     // per-block sum of exp(logit)
  float part_best[NB];    // per-block best unvisited logit
  int   part_idx[NB];     // per-block best unvisited index
  int   visited[ONUM];    // 0/1 flags
  unsigned ticket;        // phase-B completion ticket
  unsigned bar_cnt;       // barrier arrival counter
  unsigned bar_flag;      // barrier release phase
};

__device__ __forceinline__ float atom_ldf(float* p) {
  return __hip_atomic_load(p, __ATOMIC_RELAXED, AGENT);
}
__device__ __forceinline__ int atom_ldi(int* p) {
  return __hip_atomic_load(p, __ATOMIC_RELAXED, AGENT);
}
__device__ __forceinline__ void atom_stf(float* p, float v) {
  __hip_atomic_store(p, v, __ATOMIC_RELAXED, AGENT);
}
__device__ __forceinline__ void atom_sti(int* p, int v) {
  __hip_atomic_store(p, v, __ATOMIC_RELAXED, AGENT);
}

__global__ void init_kernel(Ws* ws) {
  int tid = threadIdx.x;
  for (int i = tid; i < HID; i += TPB) {
    ws->h[0][i] = 0.0f;
    ws->h[1][i] = 0.0f;
    ws->visited[i] = 0;
  }
  if (tid == 0) {
    ws->ticket = 0u;
    ws->bar_cnt = 0u;
    ws->bar_flag = 0u;
  }
}

__device__ __forceinline__ void grid_barrier(Ws* ws, unsigned phase) {
  __syncthreads();
  if (threadIdx.x == 0) {
    unsigned old = __hip_atomic_fetch_add(&ws->bar_cnt, 1u, __ATOMIC_ACQ_REL, AGENT);
    if (old == NB - 1) {
      __hip_atomic_store(&ws->bar_cnt, 0u, __ATOMIC_RELAXED, AGENT);
      __hip_atomic_store(&ws->bar_flag, phase, __ATOMIC_RELEASE, AGENT);
    } else {
      while (__hip_atomic_load(&ws->bar_flag, __ATOMIC_ACQUIRE, AGENT) < phase) {
        __builtin_amdgcn_s_sleep(1);
      }
    }
  }
  __syncthreads();
}

extern "C" __global__ void __launch_bounds__(TPB, 1)
decoder_main(const float* __restrict__ X,      // (SEQ, FEAT)
             const float* __restrict__ ENC,    // (SEQ, HID)
             const float* __restrict__ W_ih,   // (4H, FEAT)
             const float* __restrict__ W_hh,   // (4H, HID)
             const float* __restrict__ b_ih,   // (4H,)
             const float* __restrict__ b_hh,   // (4H,)
             const float* __restrict__ W_out,  // (ONUM, HID)
             const float* __restrict__ b_out,  // (ONUM,)
             float* __restrict__ out,          // 2048: [idx(1024), logp(1024)]
             Ws* __restrict__ ws)
{
  const int b   = blockIdx.x;
  const int tid = threadIdx.x;

  __shared__ float4 h_lds4[HID / 4];          // current h (shared by both phases)
  __shared__ float  gl[8][4];                 // per-row gate values (i,f,g,o)
  __shared__ float  ls_sum[8], ls_best[8];
  __shared__ int    ls_idx[8];
  __shared__ int    is_last;
  __shared__ float  cw_s[4], cw_b[4];
  __shared__ int    cw_i[4];

  // ---- Phase A mapping: 32 gate-dots x 8 lanes ----
  const int dotA = tid >> 3;            // 0..31
  const int kA   = tid & 7;             // 0..7
  const int jloc = dotA >> 2;           // 0..7 : local h row
  const int gate = dotA & 3;            // 0..3 : i,f,g,o
  const int jrow = b * 8 + jloc;        // global h row
  const int grow = gate * HID + jrow;   // row of the 4H gate matrices
  const float4* wih_row = (const float4*)(W_ih + (size_t)grow * FEAT);
  const float4* whh_row = (const float4*)(W_hh + (size_t)grow * HID);
  const float bias_g = b_ih[grow] + b_hh[grow];

  // ---- Phase B mapping: 8 logit rows x 32 lanes ----
  const int rloc = tid >> 5;            // 0..7
  const int kB   = tid & 31;            // 0..31
  const int rrow = b * 8 + rloc;        // global logit row
  const float4* wout_row = (const float4*)(W_out + (size_t)rrow * HID);
  const float bias_o = b_out[rrow];

  // h_0 = 0
  for (int i = tid; i < HID / 4; i += TPB) h_lds4[i] = make_float4(0.f, 0.f, 0.f, 0.f);
  __syncthreads();

  for (int t = 0; t < SEQ; ++t) {
    // ================= Phase A: gates -> h_t =================
    const float4* xrow = (const float4*)(X + (size_t)t * FEAT);
    float4 acc = make_float4(0.f, 0.f, 0.f, 0.f);
    #pragma unroll 4
    for (int m = 0; m < 32; ++m) {
      const int c = kA + (m << 3);
      float4 w  = whh_row[c];
      float4 hv = h_lds4[c];
      acc.x = fmaf(w.x, hv.x, acc.x);
      acc.y = fmaf(w.y, hv.y, acc.y);
      acc.z = fmaf(w.z, hv.z, acc.z);
      acc.w = fmaf(w.w, hv.w, acc.w);
    }
    #pragma unroll
    for (int m = 0; m < 8; ++m) {
      const int c = kA + (m << 3);
      float4 w  = wih_row[c];
      float4 xv = xrow[c];
      acc.x = fmaf(w.x, xv.x, acc.x);
      acc.y = fmaf(w.y, xv.y, acc.y);
      acc.z = fmaf(w.z, xv.z, acc.z);
      acc.w = fmaf(w.w, xv.w, acc.w);
    }
    float v = (acc.x + acc.y) + (acc.z + acc.w);
    v += __shfl_xor(v, 1);
    v += __shfl_xor(v, 2);
    v += __shfl_xor(v, 4);
    if (kA == 0) gl[jloc][gate] = v + bias_g;
    __syncthreads();

    if (tid < 8) {
      float ig = 1.0f / (1.0f + expf(-gl[tid][0]));
      float fg = 1.0f / (1.0f + expf(-gl[tid][1]));
      float gg = tanhf(gl[tid][2]);
      float og = 1.0f / (1.0f + expf(-gl[tid][3]));
      float c0v = ENC[(size_t)(SEQ - 1) * HID + b * 8 + tid];  // quirk: c0 every step
      float cc = fmaf(fg, c0v, ig * gg);
      float hn = og * tanhf(cc);
      atom_stf(&ws->h[(t + 1) & 1][b * 8 + tid], hn);
    }

    grid_barrier(ws, (unsigned)(t + 1));   // h_t complete everywhere

    // ---- stage full h_t into LDS (agent-scope loads bypass stale L1/L2) ----
    {
      unsigned long long* hsrc = (unsigned long long*)ws->h[(t + 1) & 1];
      for (int i = tid; i < HID / 2; i += TPB) {
        unsigned long long u = __hip_atomic_load(&hsrc[i], __ATOMIC_RELAXED, AGENT);
        float2 f2;
        __builtin_memcpy(&f2, &u, 8);
        ((float2*)h_lds4)[i] = f2;
      }
    }
    __syncthreads();

    // ================= Phase B: logits + partial softmax/argmax =================
    float4 accb = make_float4(0.f, 0.f, 0.f, 0.f);
    #pragma unroll
    for (int m = 0; m < 8; ++m) {
      const int c = kB + (m << 5);
      float4 w  = wout_row[c];
      float4 hv = h_lds4[c];
      accb.x = fmaf(w.x, hv.x, accb.x);
      accb.y = fmaf(w.y, hv.y, accb.y);
      accb.z = fmaf(w.z, hv.z, accb.z);
      accb.w = fmaf(w.w, hv.w, accb.w);
    }
    float lv = (accb.x + accb.y) + (accb.z + accb.w);
    lv += __shfl_xor(lv, 1);
    lv += __shfl_xor(lv, 2);
    lv += __shfl_xor(lv, 4);
    lv += __shfl_xor(lv, 8);
    lv += __shfl_xor(lv, 16);
    if (kB == 0) {
      float l = lv + bias_o;
      int vis = atom_ldi(&ws->visited[rrow]);
      ls_sum[rloc]  = expf(l);
      ls_best[rloc] = vis ? -FLT_MAX : l;
      ls_idx[rloc]  = rrow;
    }
    __syncthreads();

    if (tid == 0) {
      float s = 0.f, bv = -FLT_MAX;
      int bi = 0x7fffffff;
      #pragma unroll
      for (int q = 0; q < 8; ++q) {      // ascending index, strict > : first-max
        s += ls_sum[q];
        if (ls_best[q] > bv) { bv = ls_best[q]; bi = ls_idx[q]; }
      }
      atom_stf(&ws->part_sum[b],  s);
      atom_stf(&ws->part_best[b], bv);
      atom_sti(&ws->part_idx[b],  bi);
      unsigned old = __hip_atomic_fetch_add(&ws->ticket, 1u, __ATOMIC_ACQ_REL, AGENT);
      is_last = (old == NB - 1) ? 1 : 0;
    }
    __syncthreads();

    if (is_last) {   // block-uniform: this block finalizes step t
      float s = 0.f, bv = -FLT_MAX;
      int bi = 0x7fffffff;
      if (tid < NB) {
        s  = atom_ldf(&ws->part_sum[tid]);
        bv = atom_ldf(&ws->part_best[tid]);
        bi = atom_ldi(&ws->part_idx[tid]);
      }
      #pragma unroll
      for (int m = 1; m < 64; m <<= 1) {
        float s2  = __shfl_xor(s, m);
        float bv2 = __shfl_xor(bv, m);
        int   bi2 = __shfl_xor(bi, m);
        s += s2;
        if (bv2 > bv || (bv2 == bv && bi2 < bi)) { bv = bv2; bi = bi2; }
      }
      const int w = tid >> 6;
      if ((tid & 63) == 0) { cw_s[w] = s; cw_b[w] = bv; cw_i[w] = bi; }
      __syncthreads();
      if (tid == 0) {
        #pragma unroll
        for (int q = 1; q < 4; ++q) {
          s += cw_s[q];
          if (cw_b[q] > bv || (cw_b[q] == bv && cw_i[q] < bi)) { bv = cw_b[q]; bi = cw_i[q]; }
        }
        out[t]       = (float)bi;          // tour index
        out[SEQ + t] = bv - logf(s);       // logp = l_best - log(sum exp l)
        atom_sti(&ws->visited[bi], 1);
        __hip_atomic_store(&ws->ticket, 0u, __ATOMIC_RELAXED, AGENT);
      }
      // no trailing barrier needed: next step's barrier fences these updates
    }
    // h_lds4 still holds h_t -> reused as h_{t-1} by next iteration's Phase A
  }
}

extern "C" void kernel_launch(void* const* d_in, const int* in_sizes, int n_in,
                              void* d_out, int out_size, void* d_ws, size_t ws_size,
                              hipStream_t stream) {
  const float* X     = (const float*)d_in[0];
  const float* ENC   = (const float*)d_in[1];
  const float* W_ih  = (const float*)d_in[2];
  const float* W_hh  = (const float*)d_in[3];
  const float* b_ih  = (const float*)d_in[4];
  const float* b_hh  = (const float*)d_in[5];
  const float* W_out = (const float*)d_in[6];
  const float* b_out = (const float*)d_in[7];
  float* out = (float*)d_out;
  Ws* ws = (Ws*)d_ws;

  init_kernel<<<1, TPB, 0, stream>>>(ws);
  decoder_main<<<NB, TPB, 0, stream>>>(X, ENC, W_ih, W_hh, b_ih, b_hh,
                                       W_out, b_out, out, ws);
}